// Round 5
// baseline (430.894 us; speedup 1.0000x reference)
//
#include <hip/hip_runtime.h>

#define NS 115              // contributing samples (S=116, last one unused)
#define WEPS 5e-5f          // per-sample color skip
#define LOG_TSKIP -6.9078f  // chunk1 skip when T < 1e-3
#define NCELLS (128*128*128)
#define PACK_BYTES ((size_t)NCELLS * 64)
#define CPB 64              // cells per pack block (256 thr = 64 cells x 4 quarters)

typedef float f32x4 __attribute__((ext_vector_type(4)));
typedef float f32x2 __attribute__((ext_vector_type(2)));
typedef _Float16 h16x8 __attribute__((ext_vector_type(8)));
typedef _Float16 h16x4 __attribute__((ext_vector_type(4)));

struct SH9 { float a,b,c,d,e,f,g,h,i; };

__device__ __forceinline__ f32x4 load4(const float* p) { f32x4 v; __builtin_memcpy(&v, p, 16); return v; }
__device__ __forceinline__ f32x2 load2(const float* p) { f32x2 v; __builtin_memcpy(&v, p, 8);  return v; }
__device__ __forceinline__ h16x8 load8h(const _Float16* p) { h16x8 v; __builtin_memcpy(&v, p, 16); return v; }
__device__ __forceinline__ h16x4 load4h(const _Float16* p) { h16x4 v; __builtin_memcpy(&v, p, 8);  return v; }

__device__ __forceinline__ void pos_to_cell(float px, float py, float pz,
                                            int& ibase, float* wxs, float* wys, float* wzs) {
    px = fminf(fmaxf(px, 0.0f), 126.9999f);
    py = fminf(fmaxf(py, 0.0f), 126.9999f);
    pz = fminf(fmaxf(pz, 0.0f), 126.9999f);
    int ix = (int)px, iy = (int)py, iz = (int)pz;
    float wx = px - (float)ix, wy = py - (float)iy, wz = pz - (float)iz;
    ibase = (ix << 14) + (iy << 7) + iz;
    wxs[0] = 1.0f - wx; wxs[1] = wx;
    wys[0] = 1.0f - wy; wys[1] = wy;
    wzs[0] = 1.0f - wz; wzs[1] = wz;
}

// opacity trilerp on the ORIGINAL f32 array (8.4 MB, L2/L3-resident; keeps
// exponent-path precision); z-adjacent corners via dwordx2.
__device__ __forceinline__ float eval_op(float px, float py, float pz,
                                         const float* __restrict__ opa) {
    int ibase; float wxs[2], wys[2], wzs[2];
    pos_to_cell(px, py, pz, ibase, wxs, wys, wzs);
    float op = 0.0f;
    #pragma unroll
    for (int cx = 0; cx < 2; ++cx)
    #pragma unroll
    for (int cy = 0; cy < 2; ++cy) {
        int idx = ibase + (cx << 14) + (cy << 7);
        f32x2 pr = load2(opa + idx);
        float wxy = wxs[cx] * wys[cy];
        op = fmaf(wxy * wzs[0], pr.x, op);
        op = fmaf(wxy * wzs[1], pr.y, op);
    }
    return fminf(fmaxf(op, 0.0f), 100000.0f);
}

// ---- packed fp16 color: one 64-B aligned cache line per corner ----
__device__ __forceinline__ void eval_color_h(float px, float py, float pz,
                                             const _Float16* __restrict__ pack,
                                             const SH9& sh,
                                             float& cr, float& cg, float& cb) {
    int ibase; float wxs[2], wys[2], wzs[2];
    pos_to_cell(px, py, pz, ibase, wxs, wys, wzs);
    float r = 0.0f, g = 0.0f, b = 0.0f;
    #pragma unroll
    for (int cx = 0; cx < 2; ++cx)
    #pragma unroll
    for (int cy = 0; cy < 2; ++cy)
    #pragma unroll
    for (int cz = 0; cz < 2; ++cz) {
        int idx = ibase + (cx << 14) + (cy << 7) + cz;
        float wc = wxs[cx] * wys[cy] * wzs[cz];
        const _Float16* cp = pack + ((size_t)idx << 5);
        h16x8 v0 = load8h(cp);        // ch 0..7
        h16x8 v1 = load8h(cp + 8);    // ch 8..15
        h16x8 v2 = load8h(cp + 16);   // ch 16..23
        h16x4 v3 = load4h(cp + 24);   // ch 24..26 (+pad)
        float c0 = sh.a*(float)v0[0] + sh.b*(float)v0[1] + sh.c*(float)v0[2] + sh.d*(float)v0[3]
                 + sh.e*(float)v0[4] + sh.f*(float)v0[5] + sh.g*(float)v0[6] + sh.h*(float)v0[7]
                 + sh.i*(float)v1[0];
        float c1 = sh.a*(float)v1[1] + sh.b*(float)v1[2] + sh.c*(float)v1[3] + sh.d*(float)v1[4]
                 + sh.e*(float)v1[5] + sh.f*(float)v1[6] + sh.g*(float)v1[7] + sh.h*(float)v2[0]
                 + sh.i*(float)v2[1];
        float c2 = sh.a*(float)v2[2] + sh.b*(float)v2[3] + sh.c*(float)v2[4] + sh.d*(float)v2[5]
                 + sh.e*(float)v2[6] + sh.f*(float)v2[7] + sh.g*(float)v3[0] + sh.h*(float)v3[1]
                 + sh.i*(float)v3[2];
        r = fmaf(wc, c0, r);
        g = fmaf(wc, c1, g);
        b = fmaf(wc, c2, b);
    }
    cr = fminf(fmaxf(r + 0.5f, 0.0f), 100000.0f);
    cg = fminf(fmaxf(g + 0.5f, 0.0f), 100000.0f);
    cb = fminf(fmaxf(b + 0.5f, 0.0f), 100000.0f);
}

// ---- f32 fallback color (used if ws too small) ----
__device__ __forceinline__ void eval_color_f(float px, float py, float pz,
                                             const float* __restrict__ grid,
                                             const SH9& sh,
                                             float& cr, float& cg, float& cb) {
    int ibase; float wxs[2], wys[2], wzs[2];
    pos_to_cell(px, py, pz, ibase, wxs, wys, wzs);
    float r = 0.0f, g = 0.0f, b = 0.0f;
    #pragma unroll
    for (int cx = 0; cx < 2; ++cx)
    #pragma unroll
    for (int cy = 0; cy < 2; ++cy)
    #pragma unroll
    for (int cz = 0; cz < 2; ++cz) {
        int idx = ibase + (cx << 14) + (cy << 7) + cz;
        float wc = wxs[cx] * wys[cy] * wzs[cz];
        const float* cp = grid + (size_t)idx * 27;
        f32x4 v0 = load4(cp);
        f32x4 v1 = load4(cp + 4);
        f32x4 v2 = load4(cp + 8);
        f32x4 v3 = load4(cp + 12);
        f32x4 v4 = load4(cp + 16);
        f32x4 v5 = load4(cp + 20);
        f32x4 v6 = load4(cp + 23);
        float c0 = sh.a*v0.x + sh.b*v0.y + sh.c*v0.z + sh.d*v0.w
                 + sh.e*v1.x + sh.f*v1.y + sh.g*v1.z + sh.h*v1.w + sh.i*v2.x;
        float c1 = sh.a*v2.y + sh.b*v2.z + sh.c*v2.w + sh.d*v3.x
                 + sh.e*v3.y + sh.f*v3.z + sh.g*v3.w + sh.h*v4.x + sh.i*v4.y;
        float c2 = sh.a*v4.z + sh.b*v4.w + sh.c*v5.x + sh.d*v5.y
                 + sh.e*v5.z + sh.f*v5.w + sh.g*v6.y + sh.h*v6.z + sh.i*v6.w;
        r = fmaf(wc, c0, r);
        g = fmaf(wc, c1, g);
        b = fmaf(wc, c2, b);
    }
    cr = fminf(fmaxf(r + 0.5f, 0.0f), 100000.0f);
    cg = fminf(fmaxf(g + 0.5f, 0.0f), 100000.0f);
    cb = fminf(fmaxf(b + 0.5f, 0.0f), 100000.0f);
}

__device__ __forceinline__ float wave_incl_scan(float v, int lane) {
    #pragma unroll
    for (int off = 1; off < 64; off <<= 1) {
        float n = __shfl_up(v, (unsigned)off, 64);
        if (lane >= off) v += n;
    }
    return v;
}

// ---- prepass v3: conflict-free, direct-store ----
// 256 threads = 64 cells x 4 quarters. Coalesced dwordx4 span load -> LDS
// (f32 only); thread (cell,q) reads 8 floats via LDS (stride-27 = <=2-way
// alias, free), converts in registers, stores 16 B straight to global at
// cell*64 + q*16 — consecutive threads -> contiguous addresses, coalesced.
__global__ __launch_bounds__(256) void pack_kernel(const float* __restrict__ grid,
                                                   _Float16* __restrict__ pack) {
    __shared__ float s_in[CPB * 27 + 8];   // +8 pad so tail reads stay in-bounds
    const int t = threadIdx.x;
    const long long c0 = (long long)blockIdx.x * CPB;
    const float* src = grid + c0 * 27;

    // load: 1728 floats = 432 f32x4 (13824-B aligned span), coalesced
    #pragma unroll
    for (int k = 0; k < 2; ++k) {
        int idx = k * 256 + t;
        if (idx < (CPB * 27) / 4) {
            f32x4 v = load4(src + idx * 4);
            __builtin_memcpy(&s_in[idx * 4], &v, 16);
        }
    }
    __syncthreads();

    const int lc = t >> 2;           // local cell 0..63
    const int q  = t & 3;            // quarter: channels q*8 .. q*8+7
    const float* in = &s_in[lc * 27 + q * 8];
    const int nvalid = (q == 3) ? 3 : 8;   // ch 27..31 are pad
    h16x8 o;
    #pragma unroll
    for (int j = 0; j < 8; ++j) {
        float f = in[j];                       // in-bounds thanks to pad
        o[j] = (_Float16)((j < nvalid) ? f : 0.0f);
    }
    _Float16* dst = pack + (((size_t)(c0 + lc)) << 5) + q * 8;
    __builtin_memcpy(dst, &o, 16);             // coalesced dwordx4 store
}

template <bool PACKED>
__global__ __launch_bounds__(256) void rf_kernel(
    const float* __restrict__ x, const float* __restrict__ d,
    const float* __restrict__ tmin, const float* __restrict__ tmax,
    const float* __restrict__ grid, const _Float16* __restrict__ pack,
    const float* __restrict__ opa,
    float* __restrict__ out, int nrays)
{
    int gtid = blockIdx.x * blockDim.x + threadIdx.x;
    int ray = __builtin_amdgcn_readfirstlane(gtid >> 6);
    int lane = threadIdx.x & 63;
    if (ray >= nrays) return;

    float ox = x[3*ray+0], oy = x[3*ray+1], oz = x[3*ray+2];
    float ddx = d[3*ray+0], ddy = d[3*ray+1], ddz = d[3*ray+2];
    float t0 = tmin[ray], t1 = tmax[ray];
    float range = t1 - t0;
    float delta = range * 0.0078125f;

    SH9 sh;
    sh.a = 0.28209479177387814f;
    sh.b = -0.4886025119029199f * ddy;
    sh.c =  0.4886025119029199f * ddz;
    sh.d = -0.4886025119029199f * ddx;
    sh.e =  1.0925484305920792f * ddx * ddy;
    sh.f = -1.0925484305920792f * ddy * ddz;
    sh.g =  0.31539156525252005f * (2.0f*ddz*ddz - ddx*ddx - ddy*ddy);
    sh.h = -1.0925484305920792f * ddx * ddz;
    sh.i =  0.5462742152960396f * (ddx*ddx - ddy*ddy);

    float accR = 0.0f, accG = 0.0f, accB = 0.0f;

    {
        int s = lane;
        float t = range * (0.05f + (float)s * 0.0078125f) + t0;
        float px = ox + t*ddx, py = oy + t*ddy, pz = oz + t*ddz;
        float opv = eval_op(px, py, pz, opa);
        float dts = -delta * opv;
        float incl = wave_incl_scan(dts, lane);
        float cum = incl - dts;
        float total0 = __shfl(incl, 63, 64);
        float w = __expf(cum) * (1.0f - __expf(dts));
        if (w > WEPS) {
            float cr, cg, cb;
            if (PACKED) eval_color_h(px, py, pz, pack, sh, cr, cg, cb);
            else        eval_color_f(px, py, pz, grid, sh, cr, cg, cb);
            accR = w * cr; accG = w * cg; accB = w * cb;
        }
        if (total0 > LOG_TSKIP) {
            int s1 = 64 + lane;
            float dts1 = 0.0f;
            float px1 = 0.f, py1 = 0.f, pz1 = 0.f;
            if (s1 < NS) {
                float t1s = range * (0.05f + (float)s1 * 0.0078125f) + t0;
                px1 = ox + t1s*ddx; py1 = oy + t1s*ddy; pz1 = oz + t1s*ddz;
                float opv1 = eval_op(px1, py1, pz1, opa);
                dts1 = -delta * opv1;
            }
            float incl1 = wave_incl_scan(dts1, lane);
            float cum1 = total0 + incl1 - dts1;
            float w1 = __expf(cum1) * (1.0f - __expf(dts1));
            if (w1 > WEPS) {
                float cr, cg, cb;
                if (PACKED) eval_color_h(px1, py1, pz1, pack, sh, cr, cg, cb);
                else        eval_color_f(px1, py1, pz1, grid, sh, cr, cg, cb);
                accR = fmaf(w1, cr, accR);
                accG = fmaf(w1, cg, accG);
                accB = fmaf(w1, cb, accB);
            }
        }
    }

    #pragma unroll
    for (int off = 32; off > 0; off >>= 1) {
        accR += __shfl_xor(accR, off, 64);
        accG += __shfl_xor(accG, off, 64);
        accB += __shfl_xor(accB, off, 64);
    }
    if (lane == 0) {
        out[3*ray+0] = accR;
        out[3*ray+1] = accG;
        out[3*ray+2] = accB;
    }
}

extern "C" void kernel_launch(void* const* d_in, const int* in_sizes, int n_in,
                              void* d_out, int out_size, void* d_ws, size_t ws_size,
                              hipStream_t stream) {
    const float* x    = (const float*)d_in[0];
    const float* d    = (const float*)d_in[1];
    const float* tmin = (const float*)d_in[2];
    const float* tmax = (const float*)d_in[3];
    const float* grid = (const float*)d_in[4];
    const float* opa  = (const float*)d_in[5];
    float* out = (float*)d_out;

    int nrays = in_sizes[0] / 3;                 // 32768
    int threads = 256;
    int blocks = (nrays * 64 + threads - 1) / threads;   // 8192

    if (ws_size >= PACK_BYTES) {
        _Float16* pack = (_Float16*)d_ws;
        pack_kernel<<<NCELLS / CPB, 256, 0, stream>>>(grid, pack);
        rf_kernel<true><<<blocks, threads, 0, stream>>>(x, d, tmin, tmax, grid, pack, opa, out, nrays);
    } else {
        rf_kernel<false><<<blocks, threads, 0, stream>>>(x, d, tmin, tmax, grid, nullptr, opa, out, nrays);
    }
}

// Round 6
// 429.488 us; speedup vs baseline: 1.0033x; 1.0033x over previous
//
#include <hip/hip_runtime.h>

#define NS 115              // contributing samples (S=116, last one unused)
#define WEPS 5e-5f          // per-sample color skip
#define LOG_TSKIP -6.9078f  // chunk1 skip when T < 1e-3
#define NCELLS (128*128*128)
#define PACK_BYTES ((size_t)NCELLS * 64)
#define CPB 256             // cells per pack block (v4: big tile, 7 loads/lane in flight)

typedef float f32x4 __attribute__((ext_vector_type(4)));
typedef float f32x2 __attribute__((ext_vector_type(2)));
typedef _Float16 h16x8 __attribute__((ext_vector_type(8)));
typedef _Float16 h16x4 __attribute__((ext_vector_type(4)));

struct SH9 { float a,b,c,d,e,f,g,h,i; };

__device__ __forceinline__ f32x4 load4(const float* p) { f32x4 v; __builtin_memcpy(&v, p, 16); return v; }
__device__ __forceinline__ f32x2 load2(const float* p) { f32x2 v; __builtin_memcpy(&v, p, 8);  return v; }
__device__ __forceinline__ h16x8 load8h(const _Float16* p) { h16x8 v; __builtin_memcpy(&v, p, 16); return v; }
__device__ __forceinline__ h16x4 load4h(const _Float16* p) { h16x4 v; __builtin_memcpy(&v, p, 8);  return v; }

__device__ __forceinline__ void pos_to_cell(float px, float py, float pz,
                                            int& ibase, float* wxs, float* wys, float* wzs) {
    px = fminf(fmaxf(px, 0.0f), 126.9999f);
    py = fminf(fmaxf(py, 0.0f), 126.9999f);
    pz = fminf(fmaxf(pz, 0.0f), 126.9999f);
    int ix = (int)px, iy = (int)py, iz = (int)pz;
    float wx = px - (float)ix, wy = py - (float)iy, wz = pz - (float)iz;
    ibase = (ix << 14) + (iy << 7) + iz;
    wxs[0] = 1.0f - wx; wxs[1] = wx;
    wys[0] = 1.0f - wy; wys[1] = wy;
    wzs[0] = 1.0f - wz; wzs[1] = wz;
}

// opacity trilerp on the ORIGINAL f32 array (8.4 MB, L2/L3-resident; keeps
// exponent-path precision); z-adjacent corners via dwordx2.
__device__ __forceinline__ float eval_op(float px, float py, float pz,
                                         const float* __restrict__ opa) {
    int ibase; float wxs[2], wys[2], wzs[2];
    pos_to_cell(px, py, pz, ibase, wxs, wys, wzs);
    float op = 0.0f;
    #pragma unroll
    for (int cx = 0; cx < 2; ++cx)
    #pragma unroll
    for (int cy = 0; cy < 2; ++cy) {
        int idx = ibase + (cx << 14) + (cy << 7);
        f32x2 pr = load2(opa + idx);
        float wxy = wxs[cx] * wys[cy];
        op = fmaf(wxy * wzs[0], pr.x, op);
        op = fmaf(wxy * wzs[1], pr.y, op);
    }
    return fminf(fmaxf(op, 0.0f), 100000.0f);
}

// ---- packed fp16 color: one 64-B aligned cache line per corner ----
__device__ __forceinline__ void eval_color_h(float px, float py, float pz,
                                             const _Float16* __restrict__ pack,
                                             const SH9& sh,
                                             float& cr, float& cg, float& cb) {
    int ibase; float wxs[2], wys[2], wzs[2];
    pos_to_cell(px, py, pz, ibase, wxs, wys, wzs);
    float r = 0.0f, g = 0.0f, b = 0.0f;
    #pragma unroll
    for (int cx = 0; cx < 2; ++cx)
    #pragma unroll
    for (int cy = 0; cy < 2; ++cy)
    #pragma unroll
    for (int cz = 0; cz < 2; ++cz) {
        int idx = ibase + (cx << 14) + (cy << 7) + cz;
        float wc = wxs[cx] * wys[cy] * wzs[cz];
        const _Float16* cp = pack + ((size_t)idx << 5);
        h16x8 v0 = load8h(cp);        // ch 0..7
        h16x8 v1 = load8h(cp + 8);    // ch 8..15
        h16x8 v2 = load8h(cp + 16);   // ch 16..23
        h16x4 v3 = load4h(cp + 24);   // ch 24..26 (+pad)
        float c0 = sh.a*(float)v0[0] + sh.b*(float)v0[1] + sh.c*(float)v0[2] + sh.d*(float)v0[3]
                 + sh.e*(float)v0[4] + sh.f*(float)v0[5] + sh.g*(float)v0[6] + sh.h*(float)v0[7]
                 + sh.i*(float)v1[0];
        float c1 = sh.a*(float)v1[1] + sh.b*(float)v1[2] + sh.c*(float)v1[3] + sh.d*(float)v1[4]
                 + sh.e*(float)v1[5] + sh.f*(float)v1[6] + sh.g*(float)v1[7] + sh.h*(float)v2[0]
                 + sh.i*(float)v2[1];
        float c2 = sh.a*(float)v2[2] + sh.b*(float)v2[3] + sh.c*(float)v2[4] + sh.d*(float)v2[5]
                 + sh.e*(float)v2[6] + sh.f*(float)v2[7] + sh.g*(float)v3[0] + sh.h*(float)v3[1]
                 + sh.i*(float)v3[2];
        r = fmaf(wc, c0, r);
        g = fmaf(wc, c1, g);
        b = fmaf(wc, c2, b);
    }
    cr = fminf(fmaxf(r + 0.5f, 0.0f), 100000.0f);
    cg = fminf(fmaxf(g + 0.5f, 0.0f), 100000.0f);
    cb = fminf(fmaxf(b + 0.5f, 0.0f), 100000.0f);
}

// ---- f32 fallback color (used if ws too small) ----
__device__ __forceinline__ void eval_color_f(float px, float py, float pz,
                                             const float* __restrict__ grid,
                                             const SH9& sh,
                                             float& cr, float& cg, float& cb) {
    int ibase; float wxs[2], wys[2], wzs[2];
    pos_to_cell(px, py, pz, ibase, wxs, wys, wzs);
    float r = 0.0f, g = 0.0f, b = 0.0f;
    #pragma unroll
    for (int cx = 0; cx < 2; ++cx)
    #pragma unroll
    for (int cy = 0; cy < 2; ++cy)
    #pragma unroll
    for (int cz = 0; cz < 2; ++cz) {
        int idx = ibase + (cx << 14) + (cy << 7) + cz;
        float wc = wxs[cx] * wys[cy] * wzs[cz];
        const float* cp = grid + (size_t)idx * 27;
        f32x4 v0 = load4(cp);
        f32x4 v1 = load4(cp + 4);
        f32x4 v2 = load4(cp + 8);
        f32x4 v3 = load4(cp + 12);
        f32x4 v4 = load4(cp + 16);
        f32x4 v5 = load4(cp + 20);
        f32x4 v6 = load4(cp + 23);
        float c0 = sh.a*v0.x + sh.b*v0.y + sh.c*v0.z + sh.d*v0.w
                 + sh.e*v1.x + sh.f*v1.y + sh.g*v1.z + sh.h*v1.w + sh.i*v2.x;
        float c1 = sh.a*v2.y + sh.b*v2.z + sh.c*v2.w + sh.d*v3.x
                 + sh.e*v3.y + sh.f*v3.z + sh.g*v3.w + sh.h*v4.x + sh.i*v4.y;
        float c2 = sh.a*v4.z + sh.b*v4.w + sh.c*v5.x + sh.d*v5.y
                 + sh.e*v5.z + sh.f*v5.w + sh.g*v6.y + sh.h*v6.z + sh.i*v6.w;
        r = fmaf(wc, c0, r);
        g = fmaf(wc, c1, g);
        b = fmaf(wc, c2, b);
    }
    cr = fminf(fmaxf(r + 0.5f, 0.0f), 100000.0f);
    cg = fminf(fmaxf(g + 0.5f, 0.0f), 100000.0f);
    cb = fminf(fmaxf(b + 0.5f, 0.0f), 100000.0f);
}

__device__ __forceinline__ float wave_incl_scan(float v, int lane) {
    #pragma unroll
    for (int off = 1; off < 64; off <<= 1) {
        float n = __shfl_up(v, (unsigned)off, 64);
        if (lane >= off) v += n;
    }
    return v;
}

// ---- prepass v4: max memory-level parallelism ----
// 256 cells/block = 27648-B line-aligned span. Each lane issues 7 INDEPENDENT
// coalesced dwordx4 loads (112 lines in flight per wave) before the single
// barrier — the copy-microbench regime — then 4 convert iterations with
// coalesced 16-B stores (consecutive threads -> consecutive dst chunks).
__global__ __launch_bounds__(256) void pack_kernel(const float* __restrict__ grid,
                                                   _Float16* __restrict__ pack) {
    __shared__ float s_in[CPB * 27 + 8];   // 27.7 KB; +8 pad for tail reads
    const int t = threadIdx.x;
    const long long c0 = (long long)blockIdx.x * CPB;
    const float* src = grid + c0 * 27;

    // load: 6912 floats = 1728 f32x4, 7 strided (coalesced) vec4 per thread
    #pragma unroll
    for (int k = 0; k < 7; ++k) {
        int idx = k * 256 + t;
        if (idx < (CPB * 27) / 4) {
            f32x4 v = load4(src + idx * 4);
            __builtin_memcpy(&s_in[idx * 4], &v, 16);
        }
    }
    __syncthreads();

    // convert+store: 1024 (cell,quarter) tasks, 4 per thread; within each
    // iteration consecutive threads write consecutive 16-B chunks.
    #pragma unroll
    for (int i = 0; i < 4; ++i) {
        int task = i * 256 + t;
        int lc = task >> 2;          // local cell 0..255
        int q  = task & 3;           // quarter: channels q*8 .. q*8+7
        const float* in = &s_in[lc * 27 + q * 8];
        const int nvalid = (q == 3) ? 3 : 8;   // ch 27..31 are pad
        h16x8 o;
        #pragma unroll
        for (int j = 0; j < 8; ++j) {
            float f = in[j];                   // in-bounds thanks to pad
            o[j] = (_Float16)((j < nvalid) ? f : 0.0f);
        }
        _Float16* dst = pack + (((size_t)(c0 + lc)) << 5) + q * 8;
        __builtin_memcpy(dst, &o, 16);         // coalesced dwordx4 store
    }
}

template <bool PACKED>
__global__ __launch_bounds__(256) void rf_kernel(
    const float* __restrict__ x, const float* __restrict__ d,
    const float* __restrict__ tmin, const float* __restrict__ tmax,
    const float* __restrict__ grid, const _Float16* __restrict__ pack,
    const float* __restrict__ opa,
    float* __restrict__ out, int nrays)
{
    int gtid = blockIdx.x * blockDim.x + threadIdx.x;
    int ray = __builtin_amdgcn_readfirstlane(gtid >> 6);
    int lane = threadIdx.x & 63;
    if (ray >= nrays) return;

    float ox = x[3*ray+0], oy = x[3*ray+1], oz = x[3*ray+2];
    float ddx = d[3*ray+0], ddy = d[3*ray+1], ddz = d[3*ray+2];
    float t0 = tmin[ray], t1 = tmax[ray];
    float range = t1 - t0;
    float delta = range * 0.0078125f;

    SH9 sh;
    sh.a = 0.28209479177387814f;
    sh.b = -0.4886025119029199f * ddy;
    sh.c =  0.4886025119029199f * ddz;
    sh.d = -0.4886025119029199f * ddx;
    sh.e =  1.0925484305920792f * ddx * ddy;
    sh.f = -1.0925484305920792f * ddy * ddz;
    sh.g =  0.31539156525252005f * (2.0f*ddz*ddz - ddx*ddx - ddy*ddy);
    sh.h = -1.0925484305920792f * ddx * ddz;
    sh.i =  0.5462742152960396f * (ddx*ddx - ddy*ddy);

    float accR = 0.0f, accG = 0.0f, accB = 0.0f;

    {
        int s = lane;
        float t = range * (0.05f + (float)s * 0.0078125f) + t0;
        float px = ox + t*ddx, py = oy + t*ddy, pz = oz + t*ddz;
        float opv = eval_op(px, py, pz, opa);
        float dts = -delta * opv;
        float incl = wave_incl_scan(dts, lane);
        float cum = incl - dts;
        float total0 = __shfl(incl, 63, 64);
        float w = __expf(cum) * (1.0f - __expf(dts));
        if (w > WEPS) {
            float cr, cg, cb;
            if (PACKED) eval_color_h(px, py, pz, pack, sh, cr, cg, cb);
            else        eval_color_f(px, py, pz, grid, sh, cr, cg, cb);
            accR = w * cr; accG = w * cg; accB = w * cb;
        }
        if (total0 > LOG_TSKIP) {
            int s1 = 64 + lane;
            float dts1 = 0.0f;
            float px1 = 0.f, py1 = 0.f, pz1 = 0.f;
            if (s1 < NS) {
                float t1s = range * (0.05f + (float)s1 * 0.0078125f) + t0;
                px1 = ox + t1s*ddx; py1 = oy + t1s*ddy; pz1 = oz + t1s*ddz;
                float opv1 = eval_op(px1, py1, pz1, opa);
                dts1 = -delta * opv1;
            }
            float incl1 = wave_incl_scan(dts1, lane);
            float cum1 = total0 + incl1 - dts1;
            float w1 = __expf(cum1) * (1.0f - __expf(dts1));
            if (w1 > WEPS) {
                float cr, cg, cb;
                if (PACKED) eval_color_h(px1, py1, pz1, pack, sh, cr, cg, cb);
                else        eval_color_f(px1, py1, pz1, grid, sh, cr, cg, cb);
                accR = fmaf(w1, cr, accR);
                accG = fmaf(w1, cg, accG);
                accB = fmaf(w1, cb, accB);
            }
        }
    }

    #pragma unroll
    for (int off = 32; off > 0; off >>= 1) {
        accR += __shfl_xor(accR, off, 64);
        accG += __shfl_xor(accG, off, 64);
        accB += __shfl_xor(accB, off, 64);
    }
    if (lane == 0) {
        out[3*ray+0] = accR;
        out[3*ray+1] = accG;
        out[3*ray+2] = accB;
    }
}

extern "C" void kernel_launch(void* const* d_in, const int* in_sizes, int n_in,
                              void* d_out, int out_size, void* d_ws, size_t ws_size,
                              hipStream_t stream) {
    const float* x    = (const float*)d_in[0];
    const float* d    = (const float*)d_in[1];
    const float* tmin = (const float*)d_in[2];
    const float* tmax = (const float*)d_in[3];
    const float* grid = (const float*)d_in[4];
    const float* opa  = (const float*)d_in[5];
    float* out = (float*)d_out;

    int nrays = in_sizes[0] / 3;                 // 32768
    int threads = 256;
    int blocks = (nrays * 64 + threads - 1) / threads;   // 8192

    if (ws_size >= PACK_BYTES) {
        _Float16* pack = (_Float16*)d_ws;
        pack_kernel<<<NCELLS / CPB, 256, 0, stream>>>(grid, pack);
        rf_kernel<true><<<blocks, threads, 0, stream>>>(x, d, tmin, tmax, grid, pack, opa, out, nrays);
    } else {
        rf_kernel<false><<<blocks, threads, 0, stream>>>(x, d, tmin, tmax, grid, nullptr, opa, out, nrays);
    }
}

// Round 7
// 408.110 us; speedup vs baseline: 1.0558x; 1.0524x over previous
//
#include <hip/hip_runtime.h>

#define NS 115              // contributing samples (S=116, last one unused)
#define WEPS 5e-5f          // per-sample color skip
#define LOG_TSKIP -6.9078f  // chunk1 skip when T < 1e-3
#define NCELLS (128*128*128)
#define PACK_BYTES ((size_t)NCELLS * 64)
#define PACK_THREADS (2048 * 256)           // grid-stride thread count for pack
#define PACK_ITERS ((NCELLS * 4) / PACK_THREADS)   // 16 chunks/thread, exact

typedef float f32x4 __attribute__((ext_vector_type(4)));
typedef float f32x2 __attribute__((ext_vector_type(2)));
typedef _Float16 h16x8 __attribute__((ext_vector_type(8)));
typedef _Float16 h16x4 __attribute__((ext_vector_type(4)));

struct SH9 { float a,b,c,d,e,f,g,h,i; };

__device__ __forceinline__ f32x4 load4(const float* p) { f32x4 v; __builtin_memcpy(&v, p, 16); return v; }
__device__ __forceinline__ f32x2 load2(const float* p) { f32x2 v; __builtin_memcpy(&v, p, 8);  return v; }
__device__ __forceinline__ h16x8 load8h(const _Float16* p) { h16x8 v; __builtin_memcpy(&v, p, 16); return v; }
__device__ __forceinline__ h16x4 load4h(const _Float16* p) { h16x4 v; __builtin_memcpy(&v, p, 8);  return v; }
// nontemporal dwordx4 (4-B-aligned addresses are HW-legal for dwordx4)
__device__ __forceinline__ f32x4 ntload4(const float* p) {
    return __builtin_nontemporal_load((const f32x4*)p);
}

__device__ __forceinline__ void pos_to_cell(float px, float py, float pz,
                                            int& ibase, float* wxs, float* wys, float* wzs) {
    px = fminf(fmaxf(px, 0.0f), 126.9999f);
    py = fminf(fmaxf(py, 0.0f), 126.9999f);
    pz = fminf(fmaxf(pz, 0.0f), 126.9999f);
    int ix = (int)px, iy = (int)py, iz = (int)pz;
    float wx = px - (float)ix, wy = py - (float)iy, wz = pz - (float)iz;
    ibase = (ix << 14) + (iy << 7) + iz;
    wxs[0] = 1.0f - wx; wxs[1] = wx;
    wys[0] = 1.0f - wy; wys[1] = wy;
    wzs[0] = 1.0f - wz; wzs[1] = wz;
}

// opacity trilerp on the ORIGINAL f32 array (8.4 MB, L2/L3-resident; keeps
// exponent-path precision); z-adjacent corners via dwordx2.
__device__ __forceinline__ float eval_op(float px, float py, float pz,
                                         const float* __restrict__ opa) {
    int ibase; float wxs[2], wys[2], wzs[2];
    pos_to_cell(px, py, pz, ibase, wxs, wys, wzs);
    float op = 0.0f;
    #pragma unroll
    for (int cx = 0; cx < 2; ++cx)
    #pragma unroll
    for (int cy = 0; cy < 2; ++cy) {
        int idx = ibase + (cx << 14) + (cy << 7);
        f32x2 pr = load2(opa + idx);
        float wxy = wxs[cx] * wys[cy];
        op = fmaf(wxy * wzs[0], pr.x, op);
        op = fmaf(wxy * wzs[1], pr.y, op);
    }
    return fminf(fmaxf(op, 0.0f), 100000.0f);
}

// ---- packed fp16 color: one 64-B aligned cache line per corner ----
__device__ __forceinline__ void eval_color_h(float px, float py, float pz,
                                             const _Float16* __restrict__ pack,
                                             const SH9& sh,
                                             float& cr, float& cg, float& cb) {
    int ibase; float wxs[2], wys[2], wzs[2];
    pos_to_cell(px, py, pz, ibase, wxs, wys, wzs);
    float r = 0.0f, g = 0.0f, b = 0.0f;
    #pragma unroll
    for (int cx = 0; cx < 2; ++cx)
    #pragma unroll
    for (int cy = 0; cy < 2; ++cy)
    #pragma unroll
    for (int cz = 0; cz < 2; ++cz) {
        int idx = ibase + (cx << 14) + (cy << 7) + cz;
        float wc = wxs[cx] * wys[cy] * wzs[cz];
        const _Float16* cp = pack + ((size_t)idx << 5);
        h16x8 v0 = load8h(cp);        // ch 0..7
        h16x8 v1 = load8h(cp + 8);    // ch 8..15
        h16x8 v2 = load8h(cp + 16);   // ch 16..23
        h16x4 v3 = load4h(cp + 24);   // ch 24..26 (+pad)
        float c0 = sh.a*(float)v0[0] + sh.b*(float)v0[1] + sh.c*(float)v0[2] + sh.d*(float)v0[3]
                 + sh.e*(float)v0[4] + sh.f*(float)v0[5] + sh.g*(float)v0[6] + sh.h*(float)v0[7]
                 + sh.i*(float)v1[0];
        float c1 = sh.a*(float)v1[1] + sh.b*(float)v1[2] + sh.c*(float)v1[3] + sh.d*(float)v1[4]
                 + sh.e*(float)v1[5] + sh.f*(float)v1[6] + sh.g*(float)v1[7] + sh.h*(float)v2[0]
                 + sh.i*(float)v2[1];
        float c2 = sh.a*(float)v2[2] + sh.b*(float)v2[3] + sh.c*(float)v2[4] + sh.d*(float)v2[5]
                 + sh.e*(float)v2[6] + sh.f*(float)v2[7] + sh.g*(float)v3[0] + sh.h*(float)v3[1]
                 + sh.i*(float)v3[2];
        r = fmaf(wc, c0, r);
        g = fmaf(wc, c1, g);
        b = fmaf(wc, c2, b);
    }
    cr = fminf(fmaxf(r + 0.5f, 0.0f), 100000.0f);
    cg = fminf(fmaxf(g + 0.5f, 0.0f), 100000.0f);
    cb = fminf(fmaxf(b + 0.5f, 0.0f), 100000.0f);
}

// ---- f32 fallback color (used if ws too small) ----
__device__ __forceinline__ void eval_color_f(float px, float py, float pz,
                                             const float* __restrict__ grid,
                                             const SH9& sh,
                                             float& cr, float& cg, float& cb) {
    int ibase; float wxs[2], wys[2], wzs[2];
    pos_to_cell(px, py, pz, ibase, wxs, wys, wzs);
    float r = 0.0f, g = 0.0f, b = 0.0f;
    #pragma unroll
    for (int cx = 0; cx < 2; ++cx)
    #pragma unroll
    for (int cy = 0; cy < 2; ++cy)
    #pragma unroll
    for (int cz = 0; cz < 2; ++cz) {
        int idx = ibase + (cx << 14) + (cy << 7) + cz;
        float wc = wxs[cx] * wys[cy] * wzs[cz];
        const float* cp = grid + (size_t)idx * 27;
        f32x4 v0 = load4(cp);
        f32x4 v1 = load4(cp + 4);
        f32x4 v2 = load4(cp + 8);
        f32x4 v3 = load4(cp + 12);
        f32x4 v4 = load4(cp + 16);
        f32x4 v5 = load4(cp + 20);
        f32x4 v6 = load4(cp + 23);
        float c0 = sh.a*v0.x + sh.b*v0.y + sh.c*v0.z + sh.d*v0.w
                 + sh.e*v1.x + sh.f*v1.y + sh.g*v1.z + sh.h*v1.w + sh.i*v2.x;
        float c1 = sh.a*v2.y + sh.b*v2.z + sh.c*v2.w + sh.d*v3.x
                 + sh.e*v3.y + sh.f*v3.z + sh.g*v3.w + sh.h*v4.x + sh.i*v4.y;
        float c2 = sh.a*v4.z + sh.b*v4.w + sh.c*v5.x + sh.d*v5.y
                 + sh.e*v5.z + sh.f*v5.w + sh.g*v6.y + sh.h*v6.z + sh.i*v6.w;
        r = fmaf(wc, c0, r);
        g = fmaf(wc, c1, g);
        b = fmaf(wc, c2, b);
    }
    cr = fminf(fmaxf(r + 0.5f, 0.0f), 100000.0f);
    cg = fminf(fmaxf(g + 0.5f, 0.0f), 100000.0f);
    cb = fminf(fmaxf(b + 0.5f, 0.0f), 100000.0f);
}

__device__ __forceinline__ float wave_incl_scan(float v, int lane) {
    #pragma unroll
    for (int off = 1; off < 64; off <<= 1) {
        float n = __shfl_up(v, (unsigned)off, 64);
        if (lane >= off) v += n;
    }
    return v;
}

// ---- prepass v5: pure copy-regime, no LDS, no barrier ----
// Output 16-B chunk o <-> input floats [(o>>2)*27 + (o&3)*8, +8). Each thread
// streams 16 chunks (4x unrolled -> 8 loads in flight), consecutive threads
// read/write monotonically increasing addresses (27 lines per 1728-B wave
// span = ideal). Grid loads are NONTEMPORAL: the 226-MB read-once grid must
// not evict the 134-MB pack (read next by rf_kernel) from L3.
__device__ __forceinline__ void pack_one(const float* __restrict__ grid,
                                         _Float16* __restrict__ pack, int o) {
    int cell = o >> 2;
    int q = o & 3;
    int base = cell * 27;
    int offa = base + ((q == 3) ? 23 : q * 8);   // q==3 shifted -1: floats 23..26, always in-bounds
    int offb = (q == 3) ? offa : offa + 4;       // q==3: dummy same-line load (L1 hit)
    f32x4 a = ntload4(grid + offa);
    f32x4 b = ntload4(grid + offb);
    h16x8 out;
    if (q == 3) {
        out[0] = (_Float16)a.y; out[1] = (_Float16)a.z; out[2] = (_Float16)a.w;
        out[3] = (_Float16)0.f; out[4] = (_Float16)0.f; out[5] = (_Float16)0.f;
        out[6] = (_Float16)0.f; out[7] = (_Float16)0.f;
    } else {
        out[0] = (_Float16)a.x; out[1] = (_Float16)a.y; out[2] = (_Float16)a.z; out[3] = (_Float16)a.w;
        out[4] = (_Float16)b.x; out[5] = (_Float16)b.y; out[6] = (_Float16)b.z; out[7] = (_Float16)b.w;
    }
    __builtin_memcpy(pack + ((size_t)o << 3), &out, 16);
}

__global__ __launch_bounds__(256) void pack_kernel(const float* __restrict__ grid,
                                                   _Float16* __restrict__ pack) {
    int tid = blockIdx.x * blockDim.x + threadIdx.x;   // 0 .. PACK_THREADS-1
    #pragma unroll 1
    for (int i = 0; i < PACK_ITERS; i += 4) {
        #pragma unroll
        for (int j = 0; j < 4; ++j) {
            pack_one(grid, pack, tid + (i + j) * PACK_THREADS);
        }
    }
}

template <bool PACKED>
__global__ __launch_bounds__(256) void rf_kernel(
    const float* __restrict__ x, const float* __restrict__ d,
    const float* __restrict__ tmin, const float* __restrict__ tmax,
    const float* __restrict__ grid, const _Float16* __restrict__ pack,
    const float* __restrict__ opa,
    float* __restrict__ out, int nrays)
{
    int gtid = blockIdx.x * blockDim.x + threadIdx.x;
    int ray = __builtin_amdgcn_readfirstlane(gtid >> 6);
    int lane = threadIdx.x & 63;
    if (ray >= nrays) return;

    float ox = x[3*ray+0], oy = x[3*ray+1], oz = x[3*ray+2];
    float ddx = d[3*ray+0], ddy = d[3*ray+1], ddz = d[3*ray+2];
    float t0 = tmin[ray], t1 = tmax[ray];
    float range = t1 - t0;
    float delta = range * 0.0078125f;

    SH9 sh;
    sh.a = 0.28209479177387814f;
    sh.b = -0.4886025119029199f * ddy;
    sh.c =  0.4886025119029199f * ddz;
    sh.d = -0.4886025119029199f * ddx;
    sh.e =  1.0925484305920792f * ddx * ddy;
    sh.f = -1.0925484305920792f * ddy * ddz;
    sh.g =  0.31539156525252005f * (2.0f*ddz*ddz - ddx*ddx - ddy*ddy);
    sh.h = -1.0925484305920792f * ddx * ddz;
    sh.i =  0.5462742152960396f * (ddx*ddx - ddy*ddy);

    float accR = 0.0f, accG = 0.0f, accB = 0.0f;

    {
        int s = lane;
        float t = range * (0.05f + (float)s * 0.0078125f) + t0;
        float px = ox + t*ddx, py = oy + t*ddy, pz = oz + t*ddz;
        float opv = eval_op(px, py, pz, opa);
        float dts = -delta * opv;
        float incl = wave_incl_scan(dts, lane);
        float cum = incl - dts;
        float total0 = __shfl(incl, 63, 64);
        float w = __expf(cum) * (1.0f - __expf(dts));
        if (w > WEPS) {
            float cr, cg, cb;
            if (PACKED) eval_color_h(px, py, pz, pack, sh, cr, cg, cb);
            else        eval_color_f(px, py, pz, grid, sh, cr, cg, cb);
            accR = w * cr; accG = w * cg; accB = w * cb;
        }
        if (total0 > LOG_TSKIP) {
            int s1 = 64 + lane;
            float dts1 = 0.0f;
            float px1 = 0.f, py1 = 0.f, pz1 = 0.f;
            if (s1 < NS) {
                float t1s = range * (0.05f + (float)s1 * 0.0078125f) + t0;
                px1 = ox + t1s*ddx; py1 = oy + t1s*ddy; pz1 = oz + t1s*ddz;
                float opv1 = eval_op(px1, py1, pz1, opa);
                dts1 = -delta * opv1;
            }
            float incl1 = wave_incl_scan(dts1, lane);
            float cum1 = total0 + incl1 - dts1;
            float w1 = __expf(cum1) * (1.0f - __expf(dts1));
            if (w1 > WEPS) {
                float cr, cg, cb;
                if (PACKED) eval_color_h(px1, py1, pz1, pack, sh, cr, cg, cb);
                else        eval_color_f(px1, py1, pz1, grid, sh, cr, cg, cb);
                accR = fmaf(w1, cr, accR);
                accG = fmaf(w1, cg, accG);
                accB = fmaf(w1, cb, accB);
            }
        }
    }

    #pragma unroll
    for (int off = 32; off > 0; off >>= 1) {
        accR += __shfl_xor(accR, off, 64);
        accG += __shfl_xor(accG, off, 64);
        accB += __shfl_xor(accB, off, 64);
    }
    if (lane == 0) {
        out[3*ray+0] = accR;
        out[3*ray+1] = accG;
        out[3*ray+2] = accB;
    }
}

extern "C" void kernel_launch(void* const* d_in, const int* in_sizes, int n_in,
                              void* d_out, int out_size, void* d_ws, size_t ws_size,
                              hipStream_t stream) {
    const float* x    = (const float*)d_in[0];
    const float* d    = (const float*)d_in[1];
    const float* tmin = (const float*)d_in[2];
    const float* tmax = (const float*)d_in[3];
    const float* grid = (const float*)d_in[4];
    const float* opa  = (const float*)d_in[5];
    float* out = (float*)d_out;

    int nrays = in_sizes[0] / 3;                 // 32768
    int threads = 256;
    int blocks = (nrays * 64 + threads - 1) / threads;   // 8192

    if (ws_size >= PACK_BYTES) {
        _Float16* pack = (_Float16*)d_ws;
        pack_kernel<<<PACK_THREADS / 256, 256, 0, stream>>>(grid, pack);
        rf_kernel<true><<<blocks, threads, 0, stream>>>(x, d, tmin, tmax, grid, pack, opa, out, nrays);
    } else {
        rf_kernel<false><<<blocks, threads, 0, stream>>>(x, d, tmin, tmax, grid, nullptr, opa, out, nrays);
    }
}

// Round 8
// 399.956 us; speedup vs baseline: 1.0774x; 1.0204x over previous
//
#include <hip/hip_runtime.h>

#define NS 115              // contributing samples (S=116, last one unused)
#define WEPS 5e-5f          // per-sample color skip
#define LOG_TSKIP -6.9078f  // chunk1 skip when T < 1e-3
#define NCELLS (128*128*128)
#define PACK_BYTES ((size_t)NCELLS * 64)
#define NRAYS_C 32768
#define WBUF_BYTES ((size_t)NRAYS_C * 128 * 4)
#define NEED_BYTES (PACK_BYTES + WBUF_BYTES)
#define PACK_BLOCKS 2048
#define PACK_THREADS (PACK_BLOCKS * 256)
#define PACK_ITERS ((NCELLS * 4) / PACK_THREADS)   // 16 chunks/thread, exact

typedef float f32x4 __attribute__((ext_vector_type(4)));
typedef float f32x2 __attribute__((ext_vector_type(2)));
typedef _Float16 h16x8 __attribute__((ext_vector_type(8)));
typedef _Float16 h16x4 __attribute__((ext_vector_type(4)));

struct SH9 { float a,b,c,d,e,f,g,h,i; };

__device__ __forceinline__ f32x4 load4(const float* p) { f32x4 v; __builtin_memcpy(&v, p, 16); return v; }
__device__ __forceinline__ f32x2 load2(const float* p) { f32x2 v; __builtin_memcpy(&v, p, 8);  return v; }
__device__ __forceinline__ h16x8 load8h(const _Float16* p) { h16x8 v; __builtin_memcpy(&v, p, 16); return v; }
__device__ __forceinline__ h16x4 load4h(const _Float16* p) { h16x4 v; __builtin_memcpy(&v, p, 8);  return v; }
__device__ __forceinline__ f32x4 ntload4(const float* p) {
    return __builtin_nontemporal_load((const f32x4*)p);
}

__device__ __forceinline__ void pos_to_cell(float px, float py, float pz,
                                            int& ibase, float* wxs, float* wys, float* wzs) {
    px = fminf(fmaxf(px, 0.0f), 126.9999f);
    py = fminf(fmaxf(py, 0.0f), 126.9999f);
    pz = fminf(fmaxf(pz, 0.0f), 126.9999f);
    int ix = (int)px, iy = (int)py, iz = (int)pz;
    float wx = px - (float)ix, wy = py - (float)iy, wz = pz - (float)iz;
    ibase = (ix << 14) + (iy << 7) + iz;
    wxs[0] = 1.0f - wx; wxs[1] = wx;
    wys[0] = 1.0f - wy; wys[1] = wy;
    wzs[0] = 1.0f - wz; wzs[1] = wz;
}

// opacity trilerp on the ORIGINAL f32 array; z-adjacent corners via dwordx2.
__device__ __forceinline__ float eval_op(float px, float py, float pz,
                                         const float* __restrict__ opa) {
    int ibase; float wxs[2], wys[2], wzs[2];
    pos_to_cell(px, py, pz, ibase, wxs, wys, wzs);
    float op = 0.0f;
    #pragma unroll
    for (int cx = 0; cx < 2; ++cx)
    #pragma unroll
    for (int cy = 0; cy < 2; ++cy) {
        int idx = ibase + (cx << 14) + (cy << 7);
        f32x2 pr = load2(opa + idx);
        float wxy = wxs[cx] * wys[cy];
        op = fmaf(wxy * wzs[0], pr.x, op);
        op = fmaf(wxy * wzs[1], pr.y, op);
    }
    return fminf(fmaxf(op, 0.0f), 100000.0f);
}

// ---- packed fp16 color: one 64-B aligned cache line per corner ----
__device__ __forceinline__ void eval_color_h(float px, float py, float pz,
                                             const _Float16* __restrict__ pack,
                                             const SH9& sh,
                                             float& cr, float& cg, float& cb) {
    int ibase; float wxs[2], wys[2], wzs[2];
    pos_to_cell(px, py, pz, ibase, wxs, wys, wzs);
    float r = 0.0f, g = 0.0f, b = 0.0f;
    #pragma unroll
    for (int cx = 0; cx < 2; ++cx)
    #pragma unroll
    for (int cy = 0; cy < 2; ++cy)
    #pragma unroll
    for (int cz = 0; cz < 2; ++cz) {
        int idx = ibase + (cx << 14) + (cy << 7) + cz;
        float wc = wxs[cx] * wys[cy] * wzs[cz];
        const _Float16* cp = pack + ((size_t)idx << 5);
        h16x8 v0 = load8h(cp);        // ch 0..7
        h16x8 v1 = load8h(cp + 8);    // ch 8..15
        h16x8 v2 = load8h(cp + 16);   // ch 16..23
        h16x4 v3 = load4h(cp + 24);   // ch 24..26 (+pad)
        float c0 = sh.a*(float)v0[0] + sh.b*(float)v0[1] + sh.c*(float)v0[2] + sh.d*(float)v0[3]
                 + sh.e*(float)v0[4] + sh.f*(float)v0[5] + sh.g*(float)v0[6] + sh.h*(float)v0[7]
                 + sh.i*(float)v1[0];
        float c1 = sh.a*(float)v1[1] + sh.b*(float)v1[2] + sh.c*(float)v1[3] + sh.d*(float)v1[4]
                 + sh.e*(float)v1[5] + sh.f*(float)v1[6] + sh.g*(float)v1[7] + sh.h*(float)v2[0]
                 + sh.i*(float)v2[1];
        float c2 = sh.a*(float)v2[2] + sh.b*(float)v2[3] + sh.c*(float)v2[4] + sh.d*(float)v2[5]
                 + sh.e*(float)v2[6] + sh.f*(float)v2[7] + sh.g*(float)v3[0] + sh.h*(float)v3[1]
                 + sh.i*(float)v3[2];
        r = fmaf(wc, c0, r);
        g = fmaf(wc, c1, g);
        b = fmaf(wc, c2, b);
    }
    cr = fminf(fmaxf(r + 0.5f, 0.0f), 100000.0f);
    cg = fminf(fmaxf(g + 0.5f, 0.0f), 100000.0f);
    cb = fminf(fmaxf(b + 0.5f, 0.0f), 100000.0f);
}

// ---- f32 fallback color (used if ws too small) ----
__device__ __forceinline__ void eval_color_f(float px, float py, float pz,
                                             const float* __restrict__ grid,
                                             const SH9& sh,
                                             float& cr, float& cg, float& cb) {
    int ibase; float wxs[2], wys[2], wzs[2];
    pos_to_cell(px, py, pz, ibase, wxs, wys, wzs);
    float r = 0.0f, g = 0.0f, b = 0.0f;
    #pragma unroll
    for (int cx = 0; cx < 2; ++cx)
    #pragma unroll
    for (int cy = 0; cy < 2; ++cy)
    #pragma unroll
    for (int cz = 0; cz < 2; ++cz) {
        int idx = ibase + (cx << 14) + (cy << 7) + cz;
        float wc = wxs[cx] * wys[cy] * wzs[cz];
        const float* cp = grid + (size_t)idx * 27;
        f32x4 v0 = load4(cp);
        f32x4 v1 = load4(cp + 4);
        f32x4 v2 = load4(cp + 8);
        f32x4 v3 = load4(cp + 12);
        f32x4 v4 = load4(cp + 16);
        f32x4 v5 = load4(cp + 20);
        f32x4 v6 = load4(cp + 23);
        float c0 = sh.a*v0.x + sh.b*v0.y + sh.c*v0.z + sh.d*v0.w
                 + sh.e*v1.x + sh.f*v1.y + sh.g*v1.z + sh.h*v1.w + sh.i*v2.x;
        float c1 = sh.a*v2.y + sh.b*v2.z + sh.c*v2.w + sh.d*v3.x
                 + sh.e*v3.y + sh.f*v3.z + sh.g*v3.w + sh.h*v4.x + sh.i*v4.y;
        float c2 = sh.a*v4.z + sh.b*v4.w + sh.c*v5.x + sh.d*v5.y
                 + sh.e*v5.z + sh.f*v5.w + sh.g*v6.y + sh.h*v6.z + sh.i*v6.w;
        r = fmaf(wc, c0, r);
        g = fmaf(wc, c1, g);
        b = fmaf(wc, c2, b);
    }
    cr = fminf(fmaxf(r + 0.5f, 0.0f), 100000.0f);
    cg = fminf(fmaxf(g + 0.5f, 0.0f), 100000.0f);
    cb = fminf(fmaxf(b + 0.5f, 0.0f), 100000.0f);
}

__device__ __forceinline__ float wave_incl_scan(float v, int lane) {
    #pragma unroll
    for (int off = 1; off < 64; off <<= 1) {
        float n = __shfl_up(v, (unsigned)off, 64);
        if (lane >= off) v += n;
    }
    return v;
}

__device__ __forceinline__ SH9 make_sh(float ddx, float ddy, float ddz) {
    SH9 sh;
    sh.a = 0.28209479177387814f;
    sh.b = -0.4886025119029199f * ddy;
    sh.c =  0.4886025119029199f * ddz;
    sh.d = -0.4886025119029199f * ddx;
    sh.e =  1.0925484305920792f * ddx * ddy;
    sh.f = -1.0925484305920792f * ddy * ddz;
    sh.g =  0.31539156525252005f * (2.0f*ddz*ddz - ddx*ddx - ddy*ddy);
    sh.h = -1.0925484305920792f * ddx * ddz;
    sh.i =  0.5462742152960396f * (ddx*ddx - ddy*ddy);
    return sh;
}

// pack chunk o: output 16-B chunk <-> input floats [(o>>2)*27 + (o&3)*8, +8)
__device__ __forceinline__ void pack_one(const float* __restrict__ grid,
                                         _Float16* __restrict__ pack, int o) {
    int cell = o >> 2;
    int q = o & 3;
    int base = cell * 27;
    int offa = base + ((q == 3) ? 23 : q * 8);
    int offb = (q == 3) ? offa : offa + 4;
    f32x4 a = ntload4(grid + offa);
    f32x4 b = ntload4(grid + offb);
    h16x8 out;
    if (q == 3) {
        out[0] = (_Float16)a.y; out[1] = (_Float16)a.z; out[2] = (_Float16)a.w;
        out[3] = (_Float16)0.f; out[4] = (_Float16)0.f; out[5] = (_Float16)0.f;
        out[6] = (_Float16)0.f; out[7] = (_Float16)0.f;
    } else {
        out[0] = (_Float16)a.x; out[1] = (_Float16)a.y; out[2] = (_Float16)a.z; out[3] = (_Float16)a.w;
        out[4] = (_Float16)b.x; out[5] = (_Float16)b.y; out[6] = (_Float16)b.z; out[7] = (_Float16)b.w;
    }
    __builtin_memcpy(pack + ((size_t)o << 3), &out, 16);
}

// ---- fused prepass: fp16 pack (HBM-streaming) + opacity/scan (L2/L3
// latency-bound) — independent work, overlapped in one kernel. Each wave
// also computes w[ray][s] for 4 rays and stores to wbuf. w>WEPS encodes all
// gating (chunk1-taken, s<NS) for the color kernel.
__global__ __launch_bounds__(256) void pack_op_kernel(
    const float* __restrict__ grid, _Float16* __restrict__ pack,
    const float* __restrict__ x, const float* __restrict__ d,
    const float* __restrict__ tmin, const float* __restrict__ tmax,
    const float* __restrict__ opa, float* __restrict__ wbuf, int nrays)
{
    const int t = threadIdx.x;
    const int tid = blockIdx.x * 256 + t;

    // ---- pack phase: 16 chunks/thread, 8 deep (16 loads in flight) ----
    #pragma unroll 1
    for (int i = 0; i < PACK_ITERS; i += 8) {
        #pragma unroll
        for (int j = 0; j < 8; ++j)
            pack_one(grid, pack, tid + (i + j) * PACK_THREADS);
    }

    // ---- opacity + transmittance scan: 4 rays per wave ----
    const int wave = tid >> 6;           // 0..8191
    const int lane = t & 63;
    #pragma unroll 1
    for (int r = 0; r < 4; ++r) {
        int ray = __builtin_amdgcn_readfirstlane(wave * 4 + r);
        if (ray >= nrays) break;
        float ox = x[3*ray+0], oy = x[3*ray+1], oz = x[3*ray+2];
        float ddx = d[3*ray+0], ddy = d[3*ray+1], ddz = d[3*ray+2];
        float t0 = tmin[ray], t1 = tmax[ray];
        float range = t1 - t0;
        float delta = range * 0.0078125f;

        // chunk 0: samples 0..63
        float tt = range * (0.05f + (float)lane * 0.0078125f) + t0;
        float px = ox + tt*ddx, py = oy + tt*ddy, pz = oz + tt*ddz;
        float opv = eval_op(px, py, pz, opa);
        float dts = -delta * opv;
        float incl = wave_incl_scan(dts, lane);
        float cum = incl - dts;
        float total0 = __shfl(incl, 63, 64);
        float w = __expf(cum) * (1.0f - __expf(dts));
        wbuf[ray * 128 + lane] = w;

        // chunk 1: samples 64..114 (0 when transmittance dead or s>=NS)
        float w1 = 0.0f;
        if (total0 > LOG_TSKIP) {
            int s1 = 64 + lane;
            float dts1 = 0.0f;
            if (s1 < NS) {
                float t1s = range * (0.05f + (float)s1 * 0.0078125f) + t0;
                float qx = ox + t1s*ddx, qy = oy + t1s*ddy, qz = oz + t1s*ddz;
                dts1 = -delta * eval_op(qx, qy, qz, opa);
            }
            float incl1 = wave_incl_scan(dts1, lane);
            float cum1 = total0 + incl1 - dts1;
            w1 = __expf(cum1) * (1.0f - __expf(dts1));   // ==0 for s1>=NS
        }
        wbuf[ray * 128 + 64 + lane] = w1;
    }
}

// ---- color kernel: wave per ray, lane = sample; reads w, gathers packed
// fp16 cells only where w > WEPS ----
__global__ __launch_bounds__(256) void color_kernel(
    const float* __restrict__ x, const float* __restrict__ d,
    const float* __restrict__ tmin, const float* __restrict__ tmax,
    const _Float16* __restrict__ pack, const float* __restrict__ wbuf,
    float* __restrict__ out, int nrays)
{
    int gtid = blockIdx.x * blockDim.x + threadIdx.x;
    int ray = __builtin_amdgcn_readfirstlane(gtid >> 6);
    int lane = threadIdx.x & 63;
    if (ray >= nrays) return;

    float ox = x[3*ray+0], oy = x[3*ray+1], oz = x[3*ray+2];
    float ddx = d[3*ray+0], ddy = d[3*ray+1], ddz = d[3*ray+2];
    float t0 = tmin[ray], t1 = tmax[ray];
    float range = t1 - t0;
    SH9 sh = make_sh(ddx, ddy, ddz);

    float w0 = wbuf[ray * 128 + lane];
    float w1 = wbuf[ray * 128 + 64 + lane];

    float accR = 0.0f, accG = 0.0f, accB = 0.0f;
    if (w0 > WEPS) {
        float tt = range * (0.05f + (float)lane * 0.0078125f) + t0;
        float px = ox + tt*ddx, py = oy + tt*ddy, pz = oz + tt*ddz;
        float cr, cg, cb;
        eval_color_h(px, py, pz, pack, sh, cr, cg, cb);
        accR = w0 * cr; accG = w0 * cg; accB = w0 * cb;
    }
    if (w1 > WEPS) {   // implies 64+lane < NS and chunk1 taken
        float t1s = range * (0.05f + (float)(64 + lane) * 0.0078125f) + t0;
        float px = ox + t1s*ddx, py = oy + t1s*ddy, pz = oz + t1s*ddz;
        float cr, cg, cb;
        eval_color_h(px, py, pz, pack, sh, cr, cg, cb);
        accR = fmaf(w1, cr, accR);
        accG = fmaf(w1, cg, accG);
        accB = fmaf(w1, cb, accB);
    }

    #pragma unroll
    for (int off = 32; off > 0; off >>= 1) {
        accR += __shfl_xor(accR, off, 64);
        accG += __shfl_xor(accG, off, 64);
        accB += __shfl_xor(accB, off, 64);
    }
    if (lane == 0) {
        out[3*ray+0] = accR;
        out[3*ray+1] = accG;
        out[3*ray+2] = accB;
    }
}

// ---- fallback: fully-fused f32 path (ws too small) ----
__global__ __launch_bounds__(256) void rf_fallback(
    const float* __restrict__ x, const float* __restrict__ d,
    const float* __restrict__ tmin, const float* __restrict__ tmax,
    const float* __restrict__ grid, const float* __restrict__ opa,
    float* __restrict__ out, int nrays)
{
    int gtid = blockIdx.x * blockDim.x + threadIdx.x;
    int ray = __builtin_amdgcn_readfirstlane(gtid >> 6);
    int lane = threadIdx.x & 63;
    if (ray >= nrays) return;

    float ox = x[3*ray+0], oy = x[3*ray+1], oz = x[3*ray+2];
    float ddx = d[3*ray+0], ddy = d[3*ray+1], ddz = d[3*ray+2];
    float t0 = tmin[ray], t1 = tmax[ray];
    float range = t1 - t0;
    float delta = range * 0.0078125f;
    SH9 sh = make_sh(ddx, ddy, ddz);

    float accR = 0.0f, accG = 0.0f, accB = 0.0f;
    {
        float tt = range * (0.05f + (float)lane * 0.0078125f) + t0;
        float px = ox + tt*ddx, py = oy + tt*ddy, pz = oz + tt*ddz;
        float opv = eval_op(px, py, pz, opa);
        float dts = -delta * opv;
        float incl = wave_incl_scan(dts, lane);
        float cum = incl - dts;
        float total0 = __shfl(incl, 63, 64);
        float w = __expf(cum) * (1.0f - __expf(dts));
        if (w > WEPS) {
            float cr, cg, cb;
            eval_color_f(px, py, pz, grid, sh, cr, cg, cb);
            accR = w * cr; accG = w * cg; accB = w * cb;
        }
        if (total0 > LOG_TSKIP) {
            int s1 = 64 + lane;
            float dts1 = 0.0f;
            float px1 = 0.f, py1 = 0.f, pz1 = 0.f;
            if (s1 < NS) {
                float t1s = range * (0.05f + (float)s1 * 0.0078125f) + t0;
                px1 = ox + t1s*ddx; py1 = oy + t1s*ddy; pz1 = oz + t1s*ddz;
                dts1 = -delta * eval_op(px1, py1, pz1, opa);
            }
            float incl1 = wave_incl_scan(dts1, lane);
            float cum1 = total0 + incl1 - dts1;
            float w1 = __expf(cum1) * (1.0f - __expf(dts1));
            if (w1 > WEPS) {
                float cr, cg, cb;
                eval_color_f(px1, py1, pz1, grid, sh, cr, cg, cb);
                accR = fmaf(w1, cr, accR);
                accG = fmaf(w1, cg, accG);
                accB = fmaf(w1, cb, accB);
            }
        }
    }
    #pragma unroll
    for (int off = 32; off > 0; off >>= 1) {
        accR += __shfl_xor(accR, off, 64);
        accG += __shfl_xor(accG, off, 64);
        accB += __shfl_xor(accB, off, 64);
    }
    if (lane == 0) {
        out[3*ray+0] = accR;
        out[3*ray+1] = accG;
        out[3*ray+2] = accB;
    }
}

extern "C" void kernel_launch(void* const* d_in, const int* in_sizes, int n_in,
                              void* d_out, int out_size, void* d_ws, size_t ws_size,
                              hipStream_t stream) {
    const float* x    = (const float*)d_in[0];
    const float* d    = (const float*)d_in[1];
    const float* tmin = (const float*)d_in[2];
    const float* tmax = (const float*)d_in[3];
    const float* grid = (const float*)d_in[4];
    const float* opa  = (const float*)d_in[5];
    float* out = (float*)d_out;

    int nrays = in_sizes[0] / 3;                 // 32768
    int blocks = (nrays * 64 + 255) / 256;       // 8192

    if (ws_size >= NEED_BYTES && nrays <= NRAYS_C) {
        _Float16* pack = (_Float16*)d_ws;
        float* wbuf = (float*)((char*)d_ws + PACK_BYTES);
        pack_op_kernel<<<PACK_BLOCKS, 256, 0, stream>>>(grid, pack, x, d, tmin, tmax, opa, wbuf, nrays);
        color_kernel<<<blocks, 256, 0, stream>>>(x, d, tmin, tmax, pack, wbuf, out, nrays);
    } else {
        rf_fallback<<<blocks, 256, 0, stream>>>(x, d, tmin, tmax, grid, opa, out, nrays);
    }
}